// Round 3
// baseline (504.019 us; speedup 1.0000x reference)
//
#include <hip/hip_runtime.h>
#include <cstdint>

typedef unsigned short u16;
typedef unsigned int u32;
typedef __attribute__((ext_vector_type(8))) short bf16x8;
typedef __attribute__((ext_vector_type(4))) float f32x4;

#define DD 256

__device__ __forceinline__ u16 f2bf(float f) {
    u32 u = __float_as_uint(f);
    u32 r = (u + 0x7FFFu + ((u >> 16) & 1u)) >> 16;
    return (u16)r;
}
__device__ __forceinline__ float bf2f(u16 v) {
    return __uint_as_float(((u32)v) << 16);
}

// ---------------------------------------------------------------------------
// fp32 64x64-tile GEMM core (K=256) — tiny weight-fusion GEMMs only
// ---------------------------------------------------------------------------
__device__ __forceinline__ void gemm64_f32(const float* __restrict__ A,
                                           const float* __restrict__ W,
                                           float* __restrict__ C, int bm, int bn) {
    __shared__ float As[16][68];
    __shared__ float Bs[16][68];
    const int tid = threadIdx.x;
    const int tx = tid & 15, ty = tid >> 4;
    const int lm = tid >> 2, lk4 = (tid & 3) * 4;
    const int wk = tid >> 4, wn = (tid & 15) * 4;
    float acc[4][4] = {};
    for (int k0 = 0; k0 < DD; k0 += 16) {
        float4 av = *(const float4*)&A[(size_t)(bm + lm) * DD + k0 + lk4];
        float4 wv = *(const float4*)&W[(size_t)(k0 + wk) * DD + bn + wn];
        __syncthreads();
        As[lk4 + 0][lm] = av.x; As[lk4 + 1][lm] = av.y;
        As[lk4 + 2][lm] = av.z; As[lk4 + 3][lm] = av.w;
        *(float4*)&Bs[wk][wn] = wv;
        __syncthreads();
#pragma unroll
        for (int k = 0; k < 16; ++k) {
            float4 a = *(const float4*)&As[k][ty * 4];
            float4 b = *(const float4*)&Bs[k][tx * 4];
            float ar[4] = {a.x, a.y, a.z, a.w};
            float br[4] = {b.x, b.y, b.z, b.w};
#pragma unroll
            for (int i = 0; i < 4; ++i)
#pragma unroll
                for (int j = 0; j < 4; ++j)
                    acc[i][j] = fmaf(ar[i], br[j], acc[i][j]);
        }
    }
#pragma unroll
    for (int i = 0; i < 4; ++i) {
        float4 o = {acc[i][0], acc[i][1], acc[i][2], acc[i][3]};
        *(float4*)&C[(size_t)(bm + ty * 4 + i) * DD + bn + tx * 4] = o;
    }
}

// pass 1: Wf=W0@Wout, U1=W0@W1a_top, V1=W1b@Wout, U2=W0@W2a_top, V2=W2b@Wout
__global__ __launch_bounds__(256) void fuse_weights(
    const float* __restrict__ W0, const float* __restrict__ W1a,
    const float* __restrict__ W1b, const float* __restrict__ W2a,
    const float* __restrict__ W2b, const float* __restrict__ Wout,
    float* __restrict__ dst) {
    const float *P, *Q;
    switch (blockIdx.z) {
        case 0: P = W0;  Q = Wout; break;
        case 1: P = W0;  Q = W1a;  break;
        case 2: P = W1b; Q = Wout; break;
        case 3: P = W0;  Q = W2a;  break;
        default: P = W2b; Q = Wout; break;
    }
    gemm64_f32(P, Q, dst + (size_t)blockIdx.z * 65536, blockIdx.x * 64, blockIdx.y * 64);
}

// pass 2 (needs Wf, V1): P1 = Wf@W1a_bot -> slot 5, P2 = V1@W2a_bot -> slot 6
__global__ __launch_bounds__(256) void fuse_weights2(
    const float* __restrict__ FW, const float* __restrict__ W1a,
    const float* __restrict__ W2a, float* __restrict__ dst) {
    const float* P = blockIdx.z ? FW + 2 * 65536 : FW;          // V1 : Wf
    const float* Q = blockIdx.z ? W2a + 65536 : W1a + 65536;    // bottom halves
    gemm64_f32(P, Q, dst + (size_t)(5 + blockIdx.z) * 65536, blockIdx.x * 64, blockIdx.y * 64);
}

// transpose+convert 7 fused 256x256 fp32 weights -> bf16 [n][k]
__global__ __launch_bounds__(256) void transpose_all(
    const float* __restrict__ FW, u16* __restrict__ dstbase) {
    int z = blockIdx.y;
    const float* src = FW + (size_t)z * 65536;
    u16* dst = dstbase + (size_t)z * 65536;
    int t = blockIdx.x * 256 + threadIdx.x;
    int i = t >> 8, j = t & 255;
    dst[(size_t)j * DD + i] = f2bf(src[(size_t)i * DD + j]);
}

// pass 1 biases: 0:bf 1:c1 2:d1c 3:c2 4:d2c
__global__ void bias_all(const float* b0, const float* b1a, const float* b1b,
                         const float* b2a, const float* b2b, const float* bout,
                         const float* W1a, const float* W2a, const float* Wout,
                         float* BF) {
    int z = blockIdx.x, j = threadIdx.x;
    const float *b, *R, *add;
    switch (z) {
        case 0: b = b0;  R = Wout; add = bout; break;
        case 1: b = b0;  R = W1a;  add = b1a;  break;
        case 2: b = b1b; R = Wout; add = bout; break;
        case 3: b = b0;  R = W2a;  add = b2a;  break;
        default: b = b2b; R = Wout; add = bout; break;
    }
    float s = add[j];
    for (int k = 0; k < DD; ++k) s += b[k] * R[k * DD + j];
    BF[z * DD + j] = s;
}

// pass 2 biases: 5: e1 = c1 + bf@W1a_bot,  6: e2 = c2 + d1c@W2a_bot
__global__ void bias_all2(const float* BFin, const float* W1a, const float* W2a,
                          float* BF) {
    int z = blockIdx.x, j = threadIdx.x;
    const float* b   = z ? BFin + 2 * DD : BFin;          // d1c : bf
    const float* R   = z ? W2a + 65536 : W1a + 65536;     // bottom halves
    const float* add = z ? BFin + 3 * DD : BFin + 1 * DD; // c2 : c1
    float s = add[j];
    for (int k = 0; k < DD; ++k) s += b[k] * R[k * DD + j];
    BF[(5 + z) * DD + j] = s;
}

// fp32 -> bf16 bulk convert
__global__ __launch_bounds__(256) void convert_bf16(const float* __restrict__ in,
                                                    u16* __restrict__ out, long n4) {
    long i = (long)blockIdx.x * 256 + threadIdx.x;
    long stride = (long)gridDim.x * 256;
    for (; i < n4; i += stride) {
        float4 v = ((const float4*)in)[i];
        ushort4 o = {f2bf(v.x), f2bf(v.y), f2bf(v.z), f2bf(v.w)};
        ((ushort4*)out)[i] = o;
    }
}

// masked-mean gather core: bf16 src -> bf16 out
__device__ __forceinline__ void gather_core(
    const u16* __restrict__ src, const int* __restrict__ idx,
    const float* __restrict__ mask, u16* __restrict__ out, int C, int K) {
    int c = blockIdx.x * 4 + threadIdx.y;
    if (c >= C) return;
    int t = threadIdx.x;  // 0..63, 4 bf16 each
    float a0 = 0, a1 = 0, a2 = 0, a3 = 0, cnt = 0;
    for (int k = 0; k < K; ++k) {
        float m = mask[(size_t)c * K + k];
        cnt += m;
        if (m != 0.f) {
            int r = idx[(size_t)c * K + k];
            ushort4 v = *(const ushort4*)&src[(size_t)r * DD + t * 4];
            a0 += m * bf2f(v.x); a1 += m * bf2f(v.y);
            a2 += m * bf2f(v.z); a3 += m * bf2f(v.w);
        }
    }
    float inv = (cnt > 0.f) ? 1.f / fmaxf(cnt, 1.f) : 0.f;
    ushort4 o = {f2bf(a0 * inv), f2bf(a1 * inv), f2bf(a2 * inv), f2bf(a3 * inv)};
    *(ushort4*)&out[(size_t)c * DD + t * 4] = o;
}

__global__ __launch_bounds__(256) void gather_b(
    const u16* __restrict__ src, const int* __restrict__ idx,
    const float* __restrict__ mask, u16* __restrict__ out, int C, int K) {
    gather_core(src, idx, mask, out, C, K);
}

// two same-shape gathers from one source in one launch (blockIdx.y selects)
__global__ __launch_bounds__(256) void gather_pair(
    const u16* __restrict__ src,
    const int* __restrict__ i0, const float* __restrict__ m0, u16* __restrict__ o0,
    const int* __restrict__ i1, const float* __restrict__ m1, u16* __restrict__ o1,
    int C, int K) {
    if (blockIdx.y == 0) gather_core(src, i0, m0, o0, C, K);
    else                 gather_core(src, i1, m1, o1, C, K);
}

// ---------------------------------------------------------------------------
// MFMA bf16 GEMM: C[M,256] = A0@B0 (+ A1p@B1) + bias   (B transposed [n][k])
// 128x128 tile, 4 waves, BK=32, mfma_f32_16x16x32_bf16, global_load_lds w=16,
// XOR-swizzled LDS.
// ---------------------------------------------------------------------------
template<int TWO, int RELU_BF, int WF32, int WBF16>
__global__ __launch_bounds__(256) void gemm_mfma(
    const u16* __restrict__ A0, const u16* __restrict__ A1p,
    const u16* __restrict__ B0t, const u16* __restrict__ B1t,
    const float* __restrict__ bias, float* __restrict__ Cf,
    u16* __restrict__ Cb, int M) {
    __shared__ __align__(16) u16 As[4096];  // [128][32] bf16, swizzled
    __shared__ __align__(16) u16 Bs[4096];
    const int tid = threadIdx.x;
    const int wave = tid >> 6;
    const int lane = tid & 63;
    const int bm = blockIdx.x * 128;
    const int bn = blockIdx.y * 128;
    const int wr = wave >> 1, wc = wave & 1;

    const int p0 = wave * 64 + lane, p1 = p0 + 256;
    const int r0 = p0 >> 2, r1 = p1 >> 2;
    const int s0 = (p0 & 3) ^ ((r0 >> 1) & 3);
    const int s1 = (p1 & 3) ^ ((r1 >> 1) & 3);
    const size_t aoff0 = (size_t)min(bm + r0, M - 1) * DD + s0 * 8;
    const size_t aoff1 = (size_t)min(bm + r1, M - 1) * DD + s1 * 8;
    const size_t boff0 = (size_t)(bn + r0) * DD + s0 * 8;
    const size_t boff1 = (size_t)(bn + r1) * DD + s1 * 8;
    u16* AsW0 = As + wave * 512;
    u16* AsW1 = As + 2048 + wave * 512;
    u16* BsW0 = Bs + wave * 512;
    u16* BsW1 = Bs + 2048 + wave * 512;

    f32x4 acc[4][4] = {};

    const int ra = wr * 64 + (lane & 15);
    const int rb = wc * 64 + (lane & 15);
    const int sF = lane >> 4;

#define GLL(g, l) __builtin_amdgcn_global_load_lds( \
        (const __attribute__((address_space(1))) void*)(g), \
        (__attribute__((address_space(3))) void*)(l), 16, 0, 0)

    const int nparts = TWO ? 2 : 1;
    for (int part = 0; part < nparts; ++part) {
        const u16* __restrict__ A  = part ? A1p : A0;
        const u16* __restrict__ Bt = part ? B1t : B0t;
        for (int k0 = 0; k0 < DD; k0 += 32) {
            __syncthreads();
            GLL(A + aoff0 + k0, AsW0);
            GLL(A + aoff1 + k0, AsW1);
            GLL(Bt + boff0 + k0, BsW0);
            GLL(Bt + boff1 + k0, BsW1);
            __syncthreads();

            bf16x8 af[4], bfr[4];
#pragma unroll
            for (int mi = 0; mi < 4; ++mi) {
                int row = ra + mi * 16;
                int sp = sF ^ ((row >> 1) & 3);
                af[mi] = *(const bf16x8*)(As + row * 32 + sp * 8);
            }
#pragma unroll
            for (int ni = 0; ni < 4; ++ni) {
                int row = rb + ni * 16;
                int sp = sF ^ ((row >> 1) & 3);
                bfr[ni] = *(const bf16x8*)(Bs + row * 32 + sp * 8);
            }
#pragma unroll
            for (int mi = 0; mi < 4; ++mi)
#pragma unroll
                for (int ni = 0; ni < 4; ++ni)
                    acc[mi][ni] = __builtin_amdgcn_mfma_f32_16x16x32_bf16(
                        af[mi], bfr[ni], acc[mi][ni], 0, 0, 0);
        }
    }
#undef GLL

    const int col_l = bn + wc * 64 + (lane & 15);
    const int rbase = bm + wr * 64 + (lane >> 4) * 4;
#pragma unroll
    for (int mi = 0; mi < 4; ++mi) {
#pragma unroll
        for (int r = 0; r < 4; ++r) {
            int row = rbase + mi * 16 + r;
            if (row < M) {
#pragma unroll
                for (int ni = 0; ni < 4; ++ni) {
                    int col = col_l + ni * 16;
                    float v = acc[mi][ni][r] + bias[col];
                    if (WF32) Cf[(size_t)row * DD + col] = v;
                    if (WBF16) {
                        float vb = RELU_BF ? fmaxf(v, 0.f) : v;
                        Cb[(size_t)row * DD + col] = f2bf(vb);
                    }
                }
            }
        }
    }
}

extern "C" void kernel_launch(void* const* d_in, const int* in_sizes, int n_in,
                              void* d_out, int out_size, void* d_ws, size_t ws_size,
                              hipStream_t stream) {
    const float* X     = (const float*)d_in[0];
    const int*   d1_ci = (const int*)d_in[1];
    const int*   d1_bi = (const int*)d_in[2];
    const int*   d2_ci = (const int*)d_in[3];
    const int*   d2_bi = (const int*)d_in[4];
    const float* d1_cm = (const float*)d_in[5];
    const float* d1_bm = (const float*)d_in[6];
    const float* d2_cm = (const float*)d_in[7];
    const float* d2_bm = (const float*)d_in[8];
    const float* W0   = (const float*)d_in[9];
    const float* b0   = (const float*)d_in[10];
    const float* W1a  = (const float*)d_in[11];
    const float* b1a  = (const float*)d_in[12];
    const float* W1b  = (const float*)d_in[13];
    const float* b1b  = (const float*)d_in[14];
    const float* W2a  = (const float*)d_in[15];
    const float* b2a  = (const float*)d_in[16];
    const float* W2b  = (const float*)d_in[17];
    const float* b2b  = (const float*)d_in[18];
    const float* Wout = (const float*)d_in[19];
    const float* bout = (const float*)d_in[20];

    const int N  = in_sizes[0] / DD;   // 100000
    const int C1 = in_sizes[1] / 16;   // 50000
    const int C2 = in_sizes[3] / 32;   // 10000

    float* out  = (float*)d_out;
    float* emb0 = out;
    float* emb1 = out + (size_t)N * DD;
    float* emb2 = out + (size_t)(N + C1) * DD;

    // ---- workspace ----
    u16* Xb  = (u16*)d_ws;                     // [N,256] bf16
    u16* A1b = Xb  + (size_t)N * DD;           // [C1,256]
    u16* G1b = A1b + (size_t)C1 * DD;          // [C1,256]
    u16* H1b = G1b + (size_t)C1 * DD;          // [C1,256] relu(h1) bf16
    u16* WT  = H1b + (size_t)C1 * DD;          // 7 x 256x256 bf16 transposed
    float* FW = (float*)(((uintptr_t)(WT + 7 * 65536) + 15) & ~(uintptr_t)15);
    float* BF = FW + 7 * 65536;                // 7 x 256 fused biases
    // dim-2 buffers reuse A1b region (dead after h1 GEMM)
    u16* A2b = A1b;
    u16* G2b = A1b + (size_t)C2 * DD;
    u16* H2b = A1b + (size_t)2 * C2 * DD;

    u16* Wf_t = WT + 0 * 65536;
    u16* U1_t = WT + 1 * 65536;
    u16* V1_t = WT + 2 * 65536;
    u16* U2_t = WT + 3 * 65536;
    u16* V2_t = WT + 4 * 65536;
    u16* P1_t = WT + 5 * 65536;
    u16* P2_t = WT + 6 * 65536;

    // ---- weight/bias prep ----
    fuse_weights<<<dim3(4, 4, 5), 256, 0, stream>>>(W0, W1a, W1b, W2a, W2b, Wout, FW);
    fuse_weights2<<<dim3(4, 4, 2), 256, 0, stream>>>(FW, W1a, W2a, FW);
    bias_all<<<5, 256, 0, stream>>>(b0, b1a, b1b, b2a, b2b, bout, W1a, W2a, Wout, BF);
    bias_all2<<<2, 256, 0, stream>>>(BF, W1a, W2a, BF);
    transpose_all<<<dim3(256, 7), 256, 0, stream>>>(FW, WT);
    convert_bf16<<<2048, 256, 0, stream>>>(X, Xb, (long)N * 64);

    dim3 tb(256);
    // ---- dim 0: emb0 = Xb @ Wf + bf ----
    gemm_mfma<0, 0, 1, 0><<<dim3((N + 127) / 128, 2), tb, 0, stream>>>(
        Xb, nullptr, Wf_t, nullptr, BF + 0, emb0, nullptr, N);

    // ---- dim 1: A1,G1 gathered from bf16 X ----
    gather_pair<<<dim3((C1 + 3) / 4, 2), dim3(64, 4), 0, stream>>>(
        Xb, d1_ci, d1_cm, A1b, d1_bi, d1_bm, G1b, C1, 16);
    gemm_mfma<1, 1, 0, 1><<<dim3((C1 + 127) / 128, 2), tb, 0, stream>>>(
        A1b, G1b, U1_t, P1_t, BF + 5 * 256, nullptr, H1b, C1);   // e1, relu -> bf16
    gemm_mfma<0, 0, 1, 0><<<dim3((C1 + 127) / 128, 2), tb, 0, stream>>>(
        H1b, nullptr, V1_t, nullptr, BF + 2 * 256, emb1, nullptr, C1);  // d1c

    // ---- dim 2: A2 from bf16 X, G2 from bf16 relu(h1) ----
    gather_b<<<dim3((C2 + 3) / 4), dim3(64, 4), 0, stream>>>(Xb,  d2_ci, d2_cm, A2b, C2, 32);
    gather_b<<<dim3((C2 + 3) / 4), dim3(64, 4), 0, stream>>>(H1b, d2_bi, d2_bm, G2b, C2, 8);
    gemm_mfma<1, 1, 0, 1><<<dim3((C2 + 127) / 128, 2), tb, 0, stream>>>(
        A2b, G2b, U2_t, P2_t, BF + 6 * 256, nullptr, H2b, C2);   // e2, relu -> bf16
    gemm_mfma<0, 0, 1, 0><<<dim3((C2 + 127) / 128, 2), tb, 0, stream>>>(
        H2b, nullptr, V2_t, nullptr, BF + 4 * 256, emb2, nullptr, C2);  // d2c
}

// Round 4
// 364.239 us; speedup vs baseline: 1.3838x; 1.3838x over previous
//
#include <hip/hip_runtime.h>
#include <cstdint>

typedef unsigned short u16;
typedef unsigned int u32;
typedef __attribute__((ext_vector_type(8))) short bf16x8;
typedef __attribute__((ext_vector_type(4))) float f32x4;

#define DD 256

__device__ __forceinline__ u16 f2bf(float f) {
    u32 u = __float_as_uint(f);
    u32 r = (u + 0x7FFFu + ((u >> 16) & 1u)) >> 16;
    return (u16)r;
}
__device__ __forceinline__ float bf2f(u16 v) {
    return __uint_as_float(((u32)v) << 16);
}

// ---------------------------------------------------------------------------
// fp32 64x64-tile GEMM core (K=256) — tiny weight-fusion GEMMs only
// ---------------------------------------------------------------------------
__device__ __forceinline__ void gemm64_f32(const float* __restrict__ A,
                                           const float* __restrict__ W,
                                           float* __restrict__ C, int bm, int bn) {
    __shared__ float As[16][68];
    __shared__ float Bs[16][68];
    const int tid = threadIdx.x;
    const int tx = tid & 15, ty = tid >> 4;
    const int lm = tid >> 2, lk4 = (tid & 3) * 4;
    const int wk = tid >> 4, wn = (tid & 15) * 4;
    float acc[4][4] = {};
    for (int k0 = 0; k0 < DD; k0 += 16) {
        float4 av = *(const float4*)&A[(size_t)(bm + lm) * DD + k0 + lk4];
        float4 wv = *(const float4*)&W[(size_t)(k0 + wk) * DD + bn + wn];
        __syncthreads();
        As[lk4 + 0][lm] = av.x; As[lk4 + 1][lm] = av.y;
        As[lk4 + 2][lm] = av.z; As[lk4 + 3][lm] = av.w;
        *(float4*)&Bs[wk][wn] = wv;
        __syncthreads();
#pragma unroll
        for (int k = 0; k < 16; ++k) {
            float4 a = *(const float4*)&As[k][ty * 4];
            float4 b = *(const float4*)&Bs[k][tx * 4];
            float ar[4] = {a.x, a.y, a.z, a.w};
            float br[4] = {b.x, b.y, b.z, b.w};
#pragma unroll
            for (int i = 0; i < 4; ++i)
#pragma unroll
                for (int j = 0; j < 4; ++j)
                    acc[i][j] = fmaf(ar[i], br[j], acc[i][j]);
        }
    }
#pragma unroll
    for (int i = 0; i < 4; ++i) {
        float4 o = {acc[i][0], acc[i][1], acc[i][2], acc[i][3]};
        *(float4*)&C[(size_t)(bm + ty * 4 + i) * DD + bn + tx * 4] = o;
    }
}

// pass 1: Wf=W0@Wout, U1=W0@W1a_top, V1=W1b@Wout, U2=W0@W2a_top, V2=W2b@Wout
__global__ __launch_bounds__(256) void fuse_weights(
    const float* __restrict__ W0, const float* __restrict__ W1a,
    const float* __restrict__ W1b, const float* __restrict__ W2a,
    const float* __restrict__ W2b, const float* __restrict__ Wout,
    float* __restrict__ dst) {
    const float *P, *Q;
    switch (blockIdx.z) {
        case 0: P = W0;  Q = Wout; break;
        case 1: P = W0;  Q = W1a;  break;
        case 2: P = W1b; Q = Wout; break;
        case 3: P = W0;  Q = W2a;  break;
        default: P = W2b; Q = Wout; break;
    }
    gemm64_f32(P, Q, dst + (size_t)blockIdx.z * 65536, blockIdx.x * 64, blockIdx.y * 64);
}

// pass 2 (needs Wf, V1): P1 = Wf@W1a_bot -> slot 5, P2 = V1@W2a_bot -> slot 6
__global__ __launch_bounds__(256) void fuse_weights2(
    const float* __restrict__ FW, const float* __restrict__ W1a,
    const float* __restrict__ W2a, float* __restrict__ dst) {
    const float* P = blockIdx.z ? FW + 2 * 65536 : FW;          // V1 : Wf
    const float* Q = blockIdx.z ? W2a + 65536 : W1a + 65536;    // bottom halves
    gemm64_f32(P, Q, dst + (size_t)(5 + blockIdx.z) * 65536, blockIdx.x * 64, blockIdx.y * 64);
}

// transpose+convert 7 fused 256x256 fp32 weights -> bf16 [n][k]
__global__ __launch_bounds__(256) void transpose_all(
    const float* __restrict__ FW, u16* __restrict__ dstbase) {
    int z = blockIdx.y;
    const float* src = FW + (size_t)z * 65536;
    u16* dst = dstbase + (size_t)z * 65536;
    int t = blockIdx.x * 256 + threadIdx.x;
    int i = t >> 8, j = t & 255;
    dst[(size_t)j * DD + i] = f2bf(src[(size_t)i * DD + j]);
}

// pass 1 biases: 0:bf 1:c1 2:d1c 3:c2 4:d2c
__global__ void bias_all(const float* b0, const float* b1a, const float* b1b,
                         const float* b2a, const float* b2b, const float* bout,
                         const float* W1a, const float* W2a, const float* Wout,
                         float* BF) {
    int z = blockIdx.x, j = threadIdx.x;
    const float *b, *R, *add;
    switch (z) {
        case 0: b = b0;  R = Wout; add = bout; break;
        case 1: b = b0;  R = W1a;  add = b1a;  break;
        case 2: b = b1b; R = Wout; add = bout; break;
        case 3: b = b0;  R = W2a;  add = b2a;  break;
        default: b = b2b; R = Wout; add = bout; break;
    }
    float s = add[j];
    for (int k = 0; k < DD; ++k) s += b[k] * R[k * DD + j];
    BF[z * DD + j] = s;
}

// pass 2 biases: 5: e1 = c1 + bf@W1a_bot,  6: e2 = c2 + d1c@W2a_bot
__global__ void bias_all2(const float* BFin, const float* W1a, const float* W2a,
                          float* BF) {
    int z = blockIdx.x, j = threadIdx.x;
    const float* b   = z ? BFin + 2 * DD : BFin;          // d1c : bf
    const float* R   = z ? W2a + 65536 : W1a + 65536;     // bottom halves
    const float* add = z ? BFin + 3 * DD : BFin + 1 * DD; // c2 : c1
    float s = add[j];
    for (int k = 0; k < DD; ++k) s += b[k] * R[k * DD + j];
    BF[(5 + z) * DD + j] = s;
}

// fp32 -> bf16 bulk convert
__global__ __launch_bounds__(256) void convert_bf16(const float* __restrict__ in,
                                                    u16* __restrict__ out, long n4) {
    long i = (long)blockIdx.x * 256 + threadIdx.x;
    long stride = (long)gridDim.x * 256;
    for (; i < n4; i += stride) {
        float4 v = ((const float4*)in)[i];
        ushort4 o = {f2bf(v.x), f2bf(v.y), f2bf(v.z), f2bf(v.w)};
        ((ushort4*)out)[i] = o;
    }
}

// ---------------------------------------------------------------------------
// masked-mean gather, ILP version: no mask branch, all row loads of a 16-deep
// chunk issued before accumulation -> 16 outstanding loads per lane.
// blockDim (64,4): one wave per cell, 4 cells per block.
// ---------------------------------------------------------------------------
template<int K>
__global__ __launch_bounds__(256) void gatherK(
    const u16* __restrict__ src, const int* __restrict__ idx,
    const float* __restrict__ mask, u16* __restrict__ out, int C) {
    int c = blockIdx.x * 4 + threadIdx.y;
    if (c >= C) return;
    int t = threadIdx.x;  // 0..63, 4 bf16 each
    constexpr int CH = (K < 16) ? K : 16;
    float a0 = 0, a1 = 0, a2 = 0, a3 = 0, cnt = 0;
#pragma unroll
    for (int k0 = 0; k0 < K; k0 += CH) {
        int ids[CH];
        float ms[CH];
        ushort4 v[CH];
#pragma unroll
        for (int k = 0; k < CH; ++k) {
            ids[k] = idx[(size_t)c * K + k0 + k];
            ms[k] = mask[(size_t)c * K + k0 + k];
        }
#pragma unroll
        for (int k = 0; k < CH; ++k)
            v[k] = *(const ushort4*)&src[(size_t)ids[k] * DD + t * 4];
#pragma unroll
        for (int k = 0; k < CH; ++k) {
            float m = ms[k];
            cnt += m;
            a0 += m * bf2f(v[k].x); a1 += m * bf2f(v[k].y);
            a2 += m * bf2f(v[k].z); a3 += m * bf2f(v[k].w);
        }
    }
    float inv = (cnt > 0.f) ? 1.f / fmaxf(cnt, 1.f) : 0.f;
    ushort4 o = {f2bf(a0 * inv), f2bf(a1 * inv), f2bf(a2 * inv), f2bf(a3 * inv)};
    *(ushort4*)&out[(size_t)c * DD + t * 4] = o;
}

// ---------------------------------------------------------------------------
// MFMA bf16 GEMM: C[M,256] = A0@B0 (+ A1p@B1) + bias   (B transposed [n][k])
// 128x128 tile, 4 waves, BK=32, mfma_f32_16x16x32_bf16, global_load_lds w=16,
// XOR-swizzled LDS.
// ---------------------------------------------------------------------------
template<int TWO, int RELU_BF, int WF32, int WBF16>
__global__ __launch_bounds__(256) void gemm_mfma(
    const u16* __restrict__ A0, const u16* __restrict__ A1p,
    const u16* __restrict__ B0t, const u16* __restrict__ B1t,
    const float* __restrict__ bias, float* __restrict__ Cf,
    u16* __restrict__ Cb, int M) {
    __shared__ __align__(16) u16 As[4096];  // [128][32] bf16, swizzled
    __shared__ __align__(16) u16 Bs[4096];
    const int tid = threadIdx.x;
    const int wave = tid >> 6;
    const int lane = tid & 63;
    const int bm = blockIdx.x * 128;
    const int bn = blockIdx.y * 128;
    const int wr = wave >> 1, wc = wave & 1;

    const int p0 = wave * 64 + lane, p1 = p0 + 256;
    const int r0 = p0 >> 2, r1 = p1 >> 2;
    const int s0 = (p0 & 3) ^ ((r0 >> 1) & 3);
    const int s1 = (p1 & 3) ^ ((r1 >> 1) & 3);
    const size_t aoff0 = (size_t)min(bm + r0, M - 1) * DD + s0 * 8;
    const size_t aoff1 = (size_t)min(bm + r1, M - 1) * DD + s1 * 8;
    const size_t boff0 = (size_t)(bn + r0) * DD + s0 * 8;
    const size_t boff1 = (size_t)(bn + r1) * DD + s1 * 8;
    u16* AsW0 = As + wave * 512;
    u16* AsW1 = As + 2048 + wave * 512;
    u16* BsW0 = Bs + wave * 512;
    u16* BsW1 = Bs + 2048 + wave * 512;

    f32x4 acc[4][4] = {};

    const int ra = wr * 64 + (lane & 15);
    const int rb = wc * 64 + (lane & 15);
    const int sF = lane >> 4;

#define GLL(g, l) __builtin_amdgcn_global_load_lds( \
        (const __attribute__((address_space(1))) void*)(g), \
        (__attribute__((address_space(3))) void*)(l), 16, 0, 0)

    const int nparts = TWO ? 2 : 1;
    for (int part = 0; part < nparts; ++part) {
        const u16* __restrict__ A  = part ? A1p : A0;
        const u16* __restrict__ Bt = part ? B1t : B0t;
        for (int k0 = 0; k0 < DD; k0 += 32) {
            __syncthreads();
            GLL(A + aoff0 + k0, AsW0);
            GLL(A + aoff1 + k0, AsW1);
            GLL(Bt + boff0 + k0, BsW0);
            GLL(Bt + boff1 + k0, BsW1);
            __syncthreads();

            bf16x8 af[4], bfr[4];
#pragma unroll
            for (int mi = 0; mi < 4; ++mi) {
                int row = ra + mi * 16;
                int sp = sF ^ ((row >> 1) & 3);
                af[mi] = *(const bf16x8*)(As + row * 32 + sp * 8);
            }
#pragma unroll
            for (int ni = 0; ni < 4; ++ni) {
                int row = rb + ni * 16;
                int sp = sF ^ ((row >> 1) & 3);
                bfr[ni] = *(const bf16x8*)(Bs + row * 32 + sp * 8);
            }
#pragma unroll
            for (int mi = 0; mi < 4; ++mi)
#pragma unroll
                for (int ni = 0; ni < 4; ++ni)
                    acc[mi][ni] = __builtin_amdgcn_mfma_f32_16x16x32_bf16(
                        af[mi], bfr[ni], acc[mi][ni], 0, 0, 0);
        }
    }
#undef GLL

    const int col_l = bn + wc * 64 + (lane & 15);
    const int rbase = bm + wr * 64 + (lane >> 4) * 4;
#pragma unroll
    for (int mi = 0; mi < 4; ++mi) {
#pragma unroll
        for (int r = 0; r < 4; ++r) {
            int row = rbase + mi * 16 + r;
            if (row < M) {
#pragma unroll
                for (int ni = 0; ni < 4; ++ni) {
                    int col = col_l + ni * 16;
                    float v = acc[mi][ni][r] + bias[col];
                    if (WF32) Cf[(size_t)row * DD + col] = v;
                    if (WBF16) {
                        float vb = RELU_BF ? fmaxf(v, 0.f) : v;
                        Cb[(size_t)row * DD + col] = f2bf(vb);
                    }
                }
            }
        }
    }
}

extern "C" void kernel_launch(void* const* d_in, const int* in_sizes, int n_in,
                              void* d_out, int out_size, void* d_ws, size_t ws_size,
                              hipStream_t stream) {
    const float* X     = (const float*)d_in[0];
    const int*   d1_ci = (const int*)d_in[1];
    const int*   d1_bi = (const int*)d_in[2];
    const int*   d2_ci = (const int*)d_in[3];
    const int*   d2_bi = (const int*)d_in[4];
    const float* d1_cm = (const float*)d_in[5];
    const float* d1_bm = (const float*)d_in[6];
    const float* d2_cm = (const float*)d_in[7];
    const float* d2_bm = (const float*)d_in[8];
    const float* W0   = (const float*)d_in[9];
    const float* b0   = (const float*)d_in[10];
    const float* W1a  = (const float*)d_in[11];
    const float* b1a  = (const float*)d_in[12];
    const float* W1b  = (const float*)d_in[13];
    const float* b1b  = (const float*)d_in[14];
    const float* W2a  = (const float*)d_in[15];
    const float* b2a  = (const float*)d_in[16];
    const float* W2b  = (const float*)d_in[17];
    const float* b2b  = (const float*)d_in[18];
    const float* Wout = (const float*)d_in[19];
    const float* bout = (const float*)d_in[20];

    const int N  = in_sizes[0] / DD;   // 100000
    const int C1 = in_sizes[1] / 16;   // 50000
    const int C2 = in_sizes[3] / 32;   // 10000

    float* out  = (float*)d_out;
    float* emb0 = out;
    float* emb1 = out + (size_t)N * DD;
    float* emb2 = out + (size_t)(N + C1) * DD;

    // ---- workspace ----
    u16* Xb  = (u16*)d_ws;                     // [N,256] bf16
    u16* A1b = Xb  + (size_t)N * DD;           // [C1,256]
    u16* G1b = A1b + (size_t)C1 * DD;          // [C1,256]
    u16* H1b = G1b + (size_t)C1 * DD;          // [C1,256] relu(h1) bf16
    u16* WT  = H1b + (size_t)C1 * DD;          // 7 x 256x256 bf16 transposed
    float* FW = (float*)(((uintptr_t)(WT + 7 * 65536) + 15) & ~(uintptr_t)15);
    float* BF = FW + 7 * 65536;                // 7 x 256 fused biases
    // dim-2 buffers reuse A1b region (dead after h1 GEMM)
    u16* A2b = A1b;
    u16* G2b = A1b + (size_t)C2 * DD;
    u16* H2b = A1b + (size_t)2 * C2 * DD;

    u16* Wf_t = WT + 0 * 65536;
    u16* U1_t = WT + 1 * 65536;
    u16* V1_t = WT + 2 * 65536;
    u16* U2_t = WT + 3 * 65536;
    u16* V2_t = WT + 4 * 65536;
    u16* P1_t = WT + 5 * 65536;
    u16* P2_t = WT + 6 * 65536;

    // ---- weight/bias prep ----
    fuse_weights<<<dim3(4, 4, 5), 256, 0, stream>>>(W0, W1a, W1b, W2a, W2b, Wout, FW);
    fuse_weights2<<<dim3(4, 4, 2), 256, 0, stream>>>(FW, W1a, W2a, FW);
    bias_all<<<5, 256, 0, stream>>>(b0, b1a, b1b, b2a, b2b, bout, W1a, W2a, Wout, BF);
    bias_all2<<<2, 256, 0, stream>>>(BF, W1a, W2a, BF);
    transpose_all<<<dim3(256, 7), 256, 0, stream>>>(FW, WT);
    convert_bf16<<<2048, 256, 0, stream>>>(X, Xb, (long)N * 64);

    dim3 tb(256);
    dim3 gtb(64, 4);
    // ---- dim 0: emb0 = Xb @ Wf + bf ----
    gemm_mfma<0, 0, 1, 0><<<dim3((N + 127) / 128, 2), tb, 0, stream>>>(
        Xb, nullptr, Wf_t, nullptr, BF + 0, emb0, nullptr, N);

    // ---- dim 1: A1,G1 gathered from bf16 X ----
    gatherK<16><<<dim3((C1 + 3) / 4), gtb, 0, stream>>>(Xb, d1_ci, d1_cm, A1b, C1);
    gatherK<16><<<dim3((C1 + 3) / 4), gtb, 0, stream>>>(Xb, d1_bi, d1_bm, G1b, C1);
    gemm_mfma<1, 1, 0, 1><<<dim3((C1 + 127) / 128, 2), tb, 0, stream>>>(
        A1b, G1b, U1_t, P1_t, BF + 5 * 256, nullptr, H1b, C1);   // e1, relu -> bf16
    gemm_mfma<0, 0, 1, 0><<<dim3((C1 + 127) / 128, 2), tb, 0, stream>>>(
        H1b, nullptr, V1_t, nullptr, BF + 2 * 256, emb1, nullptr, C1);  // d1c

    // ---- dim 2: A2 from bf16 X, G2 from bf16 relu(h1) ----
    gatherK<32><<<dim3((C2 + 3) / 4), gtb, 0, stream>>>(Xb,  d2_ci, d2_cm, A2b, C2);
    gatherK<8><<<dim3((C2 + 3) / 4), gtb, 0, stream>>>(H1b, d2_bi, d2_bm, G2b, C2);
    gemm_mfma<1, 1, 0, 1><<<dim3((C2 + 127) / 128, 2), tb, 0, stream>>>(
        A2b, G2b, U2_t, P2_t, BF + 6 * 256, nullptr, H2b, C2);   // e2, relu -> bf16
    gemm_mfma<0, 0, 1, 0><<<dim3((C2 + 127) / 128, 2), tb, 0, stream>>>(
        H2b, nullptr, V2_t, nullptr, BF + 4 * 256, emb2, nullptr, C2);  // d2c
}